// Round 10
// baseline (398.252 us; speedup 1.0000x reference)
//
#include <hip/hip_runtime.h>

typedef __attribute__((ext_vector_type(8))) short short8;
typedef __attribute__((ext_vector_type(4))) float f32x4;
typedef __attribute__((ext_vector_type(2))) unsigned u32x2;
typedef __attribute__((ext_vector_type(4))) unsigned u32x4;

static constexpr int C_ = 128, H_ = 128, W_ = 128;
static constexpr int HW_ = H_ * W_;
static constexpr int CHW_ = C_ * HW_;

__device__ __forceinline__ unsigned short f2b(float f) {
  union { float f; unsigned u; } cv; cv.f = f;
  unsigned r = cv.u + 0x7FFFu + ((cv.u >> 16) & 1u);
  return (unsigned short)(r >> 16);
}
__device__ __forceinline__ float uasf(unsigned u) {
  union { unsigned u; float f; } cv; cv.u = u; return cv.f;
}
// swizzled byte offset within a <=64-row x 256B-row LDS tile
__device__ __forceinline__ int swzo(int pos, int byteInRow) {
  return pos * 256 + (byteInRow ^ ((pos & 7) << 4));
}

// ---------------- K1: per-(b, channel-of-concat) sums ----------------
__global__ __launch_bounds__(256) void k_pool(const float* __restrict__ x,
                                              const float* __restrict__ y,
                                              float* __restrict__ sums) {
  int blk = blockIdx.x;
  int b = blk >> 8, c = blk & 255;
  const float* src = (c < C_) ? (x + (size_t)b * CHW_ + (size_t)c * HW_)
                              : (y + (size_t)b * CHW_ + (size_t)(c - C_) * HW_);
  const float4* s4 = (const float4*)src;
  float acc = 0.f;
  for (int i = threadIdx.x; i < HW_ / 4; i += 256) {
    float4 v = s4[i];
    acc += v.x + v.y + v.z + v.w;
  }
  for (int off = 32; off; off >>= 1) acc += __shfl_down(acc, off, 64);
  __shared__ float red[4];
  int lane = threadIdx.x & 63, wv = threadIdx.x >> 6;
  if (lane == 0) red[wv] = acc;
  __syncthreads();
  if (threadIdx.x == 0) sums[blk] = red[0] + red[1] + red[2] + red[3];
}

// ---------------- K2: channel attention ----------------
__global__ __launch_bounds__(256) void k_ca(const float* __restrict__ sums,
                                            const float* __restrict__ w1,
                                            const float* __restrict__ b1,
                                            const float* __restrict__ w2,
                                            const float* __restrict__ b2,
                                            float* __restrict__ ca) {
  int b = blockIdx.x;
  __shared__ float pooled[256];
  __shared__ float hb[16];
  int t = threadIdx.x;
  pooled[t] = sums[b * 256 + t] * (1.f / 16384.f);
  __syncthreads();
  if (t < 16) {
    float s = b1[t];
    for (int j = 0; j < 256; ++j) s += w1[t * 256 + j] * pooled[j];
    hb[t] = fmaxf(s, 0.f);
  }
  __syncthreads();
  float s = b2[t];
  for (int r = 0; r < 16; ++r) s += w2[t * 16 + r] * hb[r];
  ca[b * 256 + t] = 1.f / (1.f + __expf(-s));
}

// ---------------- K3: weight prep ----------------
__global__ __launch_bounds__(128) void k_prep(
    const float* __restrict__ qpw, const float* __restrict__ kpw,
    const float* __restrict__ vpw,
    const float* __restrict__ fw, const float* __restrict__ fb,
    const float* __restrict__ ppw, const float* __restrict__ ppb,
    const float* __restrict__ cab,
    unsigned short* __restrict__ Wb, unsigned short* __restrict__ W2b,
    float* __restrict__ bc) {
  int blk = blockIdx.x, c = threadIdx.x;
  if (blk < 768) {
    int mat = blk >> 7, o = blk & 127;
    float v = 0.f;
    if (mat == 0) v = qpw[o * 128 + c];
    else if (mat == 1) v = kpw[o * 128 + c];
    else if (mat == 2) v = vpw[o * 128 + c];
    else if (mat == 3) {
      float a = 0.f;
      for (int m = 0; m < 128; ++m) a += fw[o * 384 + 256 + m] * ppw[m * 128 + c];
      v = a;
      if (c == 0) {
        float bb = fb[o];
        for (int m = 0; m < 128; ++m) bb += fw[o * 384 + 256 + m] * ppb[m];
        bc[o] = bb;
      }
    } else if (mat == 4) v = fw[o * 384 + c];
    else v = 0.f;
    Wb[((size_t)mat << 14) + o * 128 + c] = f2b(v);
  } else {
    int bb = (blk - 768) >> 7, o = blk & 127;
    W2b[((size_t)bb << 14) + o * 128 + c] =
        f2b(fw[o * 384 + 128 + c] * cab[bb * 256 + 128 + c]);
  }
}

// ---------------- K4: small-tile dw + MFMA pw q/k/v + MFMA window attn ------
// 8x4 tiles (2 windows), 256 threads, 26624B LDS.
// Plain launch_bounds(256): allocator keeps natural ~96 VGPR (no forced
// spill — the r7 failure was the ",6" min-waves hint).
// Regions: R0[0,8K)=A-Q->QS->OS ; R1[8K,16K)=A-V->VT ; R2[16K,24K)=A-K->KS ;
// halo (6x128x10 u16 = 15360B) aliases [8K,23.5K) ; SCR[24K,26K).
__global__ __launch_bounds__(256) void k_qkv_attn(
    const float* __restrict__ x, const float* __restrict__ y,
    const float* __restrict__ cab,
    const float* __restrict__ qdw, const float* __restrict__ qdb,
    const float* __restrict__ kdw, const float* __restrict__ kdb,
    const float* __restrict__ vdw, const float* __restrict__ vdb,
    const unsigned short* __restrict__ Wqkv,
    const float* __restrict__ qpb, const float* __restrict__ kpb,
    const float* __restrict__ vpb,
    unsigned short* __restrict__ outb) {
  __shared__ __align__(16) char lds[26624];
  constexpr int QS = 0, OS = 0;
  constexpr int AV = 8192, VT = 8192;
  constexpr int AK = 16384, KS = 16384;
  constexpr int HA = 8192;
  constexpr int SCR = 24576;

  const int t = threadIdx.x;
  const int l = t & 63, w = t >> 6;      // 4 waves
  const int lm = l & 15, g = l >> 4;
  const int blk = blockIdx.x;            // 4096 = 8 b (XCD) x 32 ty x 16 tx
  const int b = blk & 7, r = blk >> 3;
  const int ty = r >> 4, tx = r & 15;
  const int y0 = ty << 2, x0 = tx << 3;
  const int ct = t & 127, rt = t >> 7;   // dw: channel, row-pair
  const int mtile = w & 1, nbase = (w >> 1) * 64;
  unsigned short* hal = (unsigned short*)(lds + HA);  // row (hr,c): 10 u16

  // global f32 -> bf16 halo rows (6 hrows x 128 ch; 10 px window)
  auto halo_direct = [&](const float* src) {
    #pragma unroll
    for (int tk = 0; tk < 3; ++tk) {
      int task = t + tk * 256;           // = hr*128 + c
      int c = task & 127, hr = task >> 7;
      int gy = y0 - 1 + hr;
      bool rowok = (unsigned)gy < 128u;
      const float* rsrc = src + (size_t)c * HW_ + (size_t)gy * W_;
      f32x4 v[4];
      #pragma unroll
      for (int ck = 0; ck < 4; ++ck) {
        int gx0 = x0 - 4 + 4 * ck;
        bool ok2 = rowok && ((unsigned)gx0 < 125u);
        v[ck] = ok2 ? *(const f32x4*)(rsrc + gx0) : f32x4{0.f, 0.f, 0.f, 0.f};
      }
      int base = task * 10;              // u16 units
      const float* f = (const float*)v;  // f[i] <-> gx = x0-4+i
      #pragma unroll
      for (int e = 0; e < 5; ++e) {      // store gx = x0-1 .. x0+8
        unsigned u = (unsigned)f2b(f[2 * e + 3]) |
                     ((unsigned)f2b(f[2 * e + 4]) << 16);
        *(unsigned*)(hal + base + 2 * e) = u;
      }
    }
  };

  // q depthwise: thread (ct, rt) -> rows py=2rt,2rt+1, 8 px each
  auto dw_q2 = [&](const float* wdw, const float* bdw, const float* cas,
                   int dstOff) {
    const float* wp = wdw + ct * 9;
    float wr[9];
    #pragma unroll
    for (int k2 = 0; k2 < 9; ++k2) wr[k2] = wp[k2];
    float o0[8], o1[8];
    #pragma unroll
    for (int px = 0; px < 8; ++px) { o0[px] = 0.f; o1[px] = 0.f; }
    #pragma unroll
    for (int rr = 0; rr < 4; ++rr) {
      int base = ((2 * rt + rr) * 128 + ct) * 10;
      float rv[10];
      #pragma unroll
      for (int e = 0; e < 5; ++e) {
        unsigned pk = *(const unsigned*)(hal + base + 2 * e);
        rv[2 * e] = uasf(pk << 16);
        rv[2 * e + 1] = uasf(pk & 0xffff0000u);
      }
      if (rr < 3) {
        #pragma unroll
        for (int px = 0; px < 8; ++px)
          o0[px] += rv[px] * wr[3 * rr] + rv[px + 1] * wr[3 * rr + 1] +
                    rv[px + 2] * wr[3 * rr + 2];
      }
      if (rr > 0) {
        int rq = rr - 1;
        #pragma unroll
        for (int px = 0; px < 8; ++px)
          o1[px] += rv[px] * wr[3 * rq] + rv[px + 1] * wr[3 * rq + 1] +
                    rv[px + 2] * wr[3 * rq + 2];
      }
    }
    float cam = cas[ct], bb = bdw[ct];
    #pragma unroll
    for (int px = 0; px < 8; ++px) {
      *(unsigned short*)(lds + dstOff + swzo(2 * rt * 8 + px, 2 * ct)) =
          f2b(o0[px] * cam + bb);
      *(unsigned short*)(lds + dstOff + swzo((2 * rt + 1) * 8 + px, 2 * ct)) =
          f2b(o1[px] * cam + bb);
    }
  };

  // k/v depthwise from pre-read halo regs (hal region being overwritten)
  auto dw_from_hx = [&](const unsigned* hx, const float* wdw,
                        const float* bdw, float cam, int dstOff) {
    const float* wp = wdw + ct * 9;
    float wr[9];
    #pragma unroll
    for (int k2 = 0; k2 < 9; ++k2) wr[k2] = wp[k2];
    float o0[8], o1[8];
    #pragma unroll
    for (int px = 0; px < 8; ++px) { o0[px] = 0.f; o1[px] = 0.f; }
    #pragma unroll
    for (int rr = 0; rr < 4; ++rr) {
      float rv[10];
      #pragma unroll
      for (int e = 0; e < 5; ++e) {
        unsigned pk = hx[rr * 5 + e];
        rv[2 * e] = uasf(pk << 16);
        rv[2 * e + 1] = uasf(pk & 0xffff0000u);
      }
      if (rr < 3) {
        #pragma unroll
        for (int px = 0; px < 8; ++px)
          o0[px] += rv[px] * wr[3 * rr] + rv[px + 1] * wr[3 * rr + 1] +
                    rv[px + 2] * wr[3 * rr + 2];
      }
      if (rr > 0) {
        int rq = rr - 1;
        #pragma unroll
        for (int px = 0; px < 8; ++px)
          o1[px] += rv[px] * wr[3 * rq] + rv[px + 1] * wr[3 * rq + 1] +
                    rv[px + 2] * wr[3 * rq + 2];
      }
    }
    float bb = bdw[ct];
    #pragma unroll
    for (int px = 0; px < 8; ++px) {
      *(unsigned short*)(lds + dstOff + swzo(2 * rt * 8 + px, 2 * ct)) =
          f2b(o0[px] * cam + bb);
      *(unsigned short*)(lds + dstOff + swzo((2 * rt + 1) * 8 + px, 2 * ct)) =
          f2b(o1[px] * cam + bb);
    }
  };

  auto afrag_load = [&](int aOff, short8* a) {
    #pragma unroll
    for (int ks = 0; ks < 4; ++ks)
      a[ks] = *(const short8*)(lds + aOff +
                 swzo(mtile * 16 + lm, ks * 64 + g * 16));
  };
  auto gemm_from = [&](const short8* a, const unsigned short* Wm,
                       const float* bias, int dstOff) {
    f32x4 acc[4];
    #pragma unroll
    for (int nt = 0; nt < 4; ++nt) acc[nt] = f32x4{0.f, 0.f, 0.f, 0.f};
    #pragma unroll
    for (int ks = 0; ks < 4; ++ks) {
      short8 wf[4];
      #pragma unroll
      for (int nt = 0; nt < 4; ++nt)
        wf[nt] = *(const short8*)(Wm + (nbase + nt * 16 + lm) * 128 +
                                  ks * 32 + g * 8);
      #pragma unroll
      for (int nt = 0; nt < 4; ++nt)
        acc[nt] = __builtin_amdgcn_mfma_f32_16x16x32_bf16(a[ks], wf[nt], acc[nt], 0, 0, 0);
    }
    #pragma unroll
    for (int nt = 0; nt < 4; ++nt) {
      int ch = nbase + nt * 16 + lm;
      float bv = bias[ch];
      #pragma unroll
      for (int rr = 0; rr < 4; ++rr) {
        int pos = mtile * 16 + g * 4 + rr;
        *(unsigned short*)(lds + dstOff + swzo(pos, 2 * ch)) =
            f2b(acc[nt][rr] + bv);
      }
    }
  };
  // V gemm -> VT[win][ch][kp] (pitch 32B): win=g&1, kp=mtile*8+(g>>1)*4+rr
  auto gemm_v_from = [&](const short8* a, const unsigned short* Wm,
                         const float* bias) {
    f32x4 acc[4];
    #pragma unroll
    for (int nt = 0; nt < 4; ++nt) acc[nt] = f32x4{0.f, 0.f, 0.f, 0.f};
    #pragma unroll
    for (int ks = 0; ks < 4; ++ks) {
      short8 wf[4];
      #pragma unroll
      for (int nt = 0; nt < 4; ++nt)
        wf[nt] = *(const short8*)(Wm + (nbase + nt * 16 + lm) * 128 +
                                  ks * 32 + g * 8);
      #pragma unroll
      for (int nt = 0; nt < 4; ++nt)
        acc[nt] = __builtin_amdgcn_mfma_f32_16x16x32_bf16(a[ks], wf[nt], acc[nt], 0, 0, 0);
    }
    int win = g & 1;
    int kpb = mtile * 8 + (g >> 1) * 4;
    #pragma unroll
    for (int nt = 0; nt < 4; ++nt) {
      int ch = nbase + nt * 16 + lm;
      float bv = bias[ch];
      unsigned lo = (unsigned)f2b(acc[nt][0] + bv) |
                    ((unsigned)f2b(acc[nt][1] + bv) << 16);
      unsigned hi = (unsigned)f2b(acc[nt][2] + bv) |
                    ((unsigned)f2b(acc[nt][3] + bv) << 16);
      *(u32x2*)(lds + VT + win * 4096 + ch * 32 + 2 * kpb) = u32x2{lo, hi};
    }
  };

  const float* cax = cab + b * 256;
  const float* cay = cax + 128;
  const float* xb = x + (size_t)b * CHW_;
  const float* yb = y + (size_t)b * CHW_;

  halo_direct(yb);                       // P0
  __syncthreads();
  dw_q2(qdw, qdb, cay, QS);              // P1: A-Q (R0)
  __syncthreads();
  short8 aq[4];                          // P2: stage A-Q frags; x-halo
  afrag_load(QS, aq);
  halo_direct(xb);
  __syncthreads();
  gemm_from(aq, Wqkv, qpb, QS);          // P3: QS over R0; pre-read x-halo
  unsigned hx[20];
  #pragma unroll
  for (int rr = 0; rr < 4; ++rr) {
    int base = ((2 * rt + rr) * 128 + ct) * 10;
    #pragma unroll
    for (int e = 0; e < 5; ++e)
      hx[rr * 5 + e] = *(const unsigned*)(hal + base + 2 * e);
  }
  __syncthreads();
  {                                      // P4: A-K, A-V over dead halo
    float cam = cax[ct];
    dw_from_hx(hx, kdw, kdb, cam, AK);
    dw_from_hx(hx, vdw, vdb, cam, AV);
  }
  __syncthreads();
  short8 ak[4], av4[4];                  // P5
  afrag_load(AK, ak);
  afrag_load(AV, av4);
  __syncthreads();
  gemm_from(ak, Wqkv + 16384, kpb, KS);  // P6: KS over R2, VT over R1
  gemm_v_from(av4, Wqkv + 32768, vpb);
  __syncthreads();

  // P7: window attention — wave handles heads {2w,2w+1} x windows {0,1}
  u32x2 oac[4];
  {
    char* scr = lds + SCR + w * 512;
    const short8 zz = {};
    #pragma unroll
    for (int wi = 0; wi < 4; ++wi) {
      int win = wi & 1, h = w * 2 + (wi >> 1);
      int chb = h * 32;
      int rowp = (lm >> 2) * 8 + win * 4 + (lm & 3);
      short8 avf = zz, bvf = zz;
      if (g < 2) {
        avf = *(const short8*)(lds + KS + swzo(rowp, chb + g * 16));
        bvf = *(const short8*)(lds + QS + swzo(rowp, chb + g * 16));
      }
      f32x4 st = __builtin_amdgcn_mfma_f32_16x16x32_bf16(
          avf, bvf, f32x4{0.f, 0.f, 0.f, 0.f}, 0, 0, 0);
      float s0 = st[0] * 0.25f, s1 = st[1] * 0.25f,
            s2 = st[2] * 0.25f, s3 = st[3] * 0.25f;
      float mx = fmaxf(fmaxf(s0, s1), fmaxf(s2, s3));
      mx = fmaxf(mx, __shfl_xor(mx, 16, 64));
      mx = fmaxf(mx, __shfl_xor(mx, 32, 64));
      float e0 = __expf(s0 - mx), e1 = __expf(s1 - mx),
            e2 = __expf(s2 - mx), e3 = __expf(s3 - mx);
      float sm = e0 + e1 + e2 + e3;
      sm += __shfl_xor(sm, 16, 64);
      sm += __shfl_xor(sm, 32, 64);
      float rl = 1.f / sm;
      unsigned p0 = (unsigned)f2b(e0 * rl) | ((unsigned)f2b(e1 * rl) << 16);
      unsigned p1 = (unsigned)f2b(e2 * rl) | ((unsigned)f2b(e3 * rl) << 16);
      *(u32x2*)(scr + lm * 32 + g * 8) = u32x2{p0, p1};
      short8 pb2 = zz, va = zz;
      if (g < 2) {
        pb2 = *(const short8*)(scr + lm * 32 + g * 16);
        int ch = h * 16 + lm;
        va = *(const short8*)(lds + VT + win * 4096 + ch * 32 + g * 16);
      }
      f32x4 ot = __builtin_amdgcn_mfma_f32_16x16x32_bf16(
          va, pb2, f32x4{0.f, 0.f, 0.f, 0.f}, 0, 0, 0);
      unsigned o0 = (unsigned)f2b(ot[0]) | ((unsigned)f2b(ot[1]) << 16);
      unsigned o1 = (unsigned)f2b(ot[2]) | ((unsigned)f2b(ot[3]) << 16);
      oac[wi] = u32x2{o0, o1};
    }
  }
  __syncthreads();
  {                                      // P8: stage over dead QS
    #pragma unroll
    for (int wi = 0; wi < 4; ++wi) {
      int win = wi & 1, h = w * 2 + (wi >> 1);
      int rowp = (lm >> 2) * 8 + win * 4 + (lm & 3);
      *(u32x2*)(lds + OS + swzo(rowp, h * 32 + g * 8)) = oac[wi];
    }
  }
  __syncthreads();
  {                                      // P9: 16B global writes
    unsigned short* dst = outb + (size_t)b * CHW_ + (size_t)ct * HW_;
    #pragma unroll
    for (int i = 0; i < 2; ++i) {
      int py = 2 * rt + i;
      unsigned v[4];
      #pragma unroll
      for (int j = 0; j < 4; ++j) {
        unsigned lo = *(const unsigned short*)(lds + OS + swzo(py * 8 + 2 * j, 2 * ct));
        unsigned hi = *(const unsigned short*)(lds + OS + swzo(py * 8 + 2 * j + 1, 2 * ct));
        v[j] = lo | (hi << 16);
      }
      *(u32x4*)(dst + (size_t)(y0 + py) * W_ + x0) = u32x4{v[0], v[1], v[2], v[3]};
    }
  }
}

// ---------------- K5: proj-dw + 3 accumulated MFMA GEMMs + BN + ReLU --------
// 16x2 tiles, 256 threads, 28672B LDS, plain launch_bounds(256).
// A1[0,8K); halo (4x128x20 u16 = 20480B) at 8K, aliased by fst
// (32x130 f32 = 16640B).
__global__ __launch_bounds__(256) void k_final(
    const float* __restrict__ x, const float* __restrict__ y,
    const unsigned short* __restrict__ outb,
    const float* __restrict__ pdw, const float* __restrict__ pdb,
    const unsigned short* __restrict__ W3,
    const unsigned short* __restrict__ W2b,
    const float* __restrict__ bc,
    const float* __restrict__ bng, const float* __restrict__ bnb,
    const float* __restrict__ bnm, const float* __restrict__ bnv,
    float* __restrict__ outp) {
  __shared__ __align__(16) char lds[28672];
  constexpr int A1 = 0, HA = 8192;

  const int t = threadIdx.x;
  const int l = t & 63, w = t >> 6;
  const int lm = l & 15, g = l >> 4;
  const int blk = blockIdx.x;            // 4096 = 8 b x 64 ty x 8 tx
  const int b = blk & 7, r = blk >> 3;
  const int ty = r >> 3, tx = r & 7;
  const int y0 = ty << 1, x0 = tx << 4;
  const int ct = t & 127, rt = t >> 7;   // py = rt
  unsigned short* hal = (unsigned short*)(lds + HA);  // row (hr,c): 20 u16
  const int mtile = w & 1, nbase = (w >> 1) * 64;

  f32x4 acc[4];
  #pragma unroll
  for (int nt = 0; nt < 4; ++nt) acc[nt] = f32x4{0.f, 0.f, 0.f, 0.f};

  auto gemm_acc = [&](const unsigned short* Wm) {
    #pragma unroll
    for (int ks = 0; ks < 4; ++ks) {
      short8 wf[4];
      #pragma unroll
      for (int nt = 0; nt < 4; ++nt)
        wf[nt] = *(const short8*)(Wm + (nbase + nt * 16 + lm) * 128 +
                                  ks * 32 + g * 8);
      short8 a = *(const short8*)(lds + A1 +
                   swzo(mtile * 16 + lm, ks * 64 + g * 16));
      #pragma unroll
      for (int nt = 0; nt < 4; ++nt)
        acc[nt] = __builtin_amdgcn_mfma_f32_16x16x32_bf16(a, wf[nt], acc[nt], 0, 0, 0);
    }
  };

  const size_t gbase = (size_t)b * CHW_ + (size_t)ct * HW_ +
                       (size_t)(y0 + rt) * W_ + x0;

  // P0: A1 <- x*y ; outb halo (4 hrows x 128 ch, 20-px window) -> LDS
  #pragma unroll
  for (int e = 0; e < 4; ++e) {
    f32x4 xv = *(const f32x4*)(x + gbase + 4 * e);
    f32x4 yv = *(const f32x4*)(y + gbase + 4 * e);
    #pragma unroll
    for (int j = 0; j < 4; ++j)
      *(unsigned short*)(lds + A1 + swzo(rt * 16 + 4 * e + j, 2 * ct)) =
          f2b(xv[j] * yv[j]);
  }
  #pragma unroll
  for (int tk = 0; tk < 2; ++tk) {
    int task = t + tk * 256;             // = hr*128 + c
    int c = task & 127, hr = task >> 7;
    int gy = y0 - 1 + hr;
    bool rowok = (unsigned)gy < 128u;
    const unsigned short* hsrc =
        outb + (size_t)b * CHW_ + (size_t)c * HW_ + (size_t)gy * W_;
    int base = task * 20;
    #pragma unroll
    for (int e = 0; e < 10; ++e) {       // gx = x0-2 .. x0+17
      int gx0 = x0 - 2 + 2 * e;
      bool okp = rowok && ((unsigned)gx0 < 127u);
      unsigned u = okp ? *(const unsigned*)(hsrc + gx0) : 0u;
      *(unsigned*)(hal + base + 2 * e) = u;
    }
  }
  __syncthreads();
  gemm_acc(W3 + 16384);                  // fw1 on x*y
  __syncthreads();
  // P2: A1 <- y
  #pragma unroll
  for (int e = 0; e < 4; ++e) {
    f32x4 yv = *(const f32x4*)(y + gbase + 4 * e);
    #pragma unroll
    for (int j = 0; j < 4; ++j)
      *(unsigned short*)(lds + A1 + swzo(rt * 16 + 4 * e + j, 2 * ct)) =
          f2b(yv[j]);
  }
  __syncthreads();
  gemm_acc(W2b + ((size_t)b << 14));     // fw2 * diag(ca_y)
  __syncthreads();
  // P4: proj-dw (py = rt, 16 px) from halo rows rt..rt+2
  {
    const float* wp = pdw + ct * 9;
    float wr[9];
    #pragma unroll
    for (int k2 = 0; k2 < 9; ++k2) wr[k2] = wp[k2];
    float bb = pdb[ct];
    float o[16];
    #pragma unroll
    for (int px = 0; px < 16; ++px) o[px] = 0.f;
    #pragma unroll
    for (int rr = 0; rr < 3; ++rr) {
      int base = ((rt + rr) * 128 + ct) * 20;
      float rv[20];
      #pragma unroll
      for (int e = 0; e < 10; ++e) {
        unsigned pk = *(const unsigned*)(hal + base + 2 * e);
        rv[2 * e] = uasf(pk << 16);
        rv[2 * e + 1] = uasf(pk & 0xffff0000u);
      }
      #pragma unroll
      for (int px = 0; px < 16; ++px)
        o[px] += rv[px + 1] * wr[3 * rr] + rv[px + 2] * wr[3 * rr + 1] +
                 rv[px + 3] * wr[3 * rr + 2];
    }
    #pragma unroll
    for (int px = 0; px < 16; ++px)
      *(unsigned short*)(lds + A1 + swzo(rt * 16 + px, 2 * ct)) =
          f2b(o[px] + bb);
  }
  __syncthreads();
  gemm_acc(W3);                          // folded Wc
  // epilogue -> fst (f32 pitch 130, over dead halo)
  float* fst = (float*)(lds + HA);
  #pragma unroll
  for (int nt = 0; nt < 4; ++nt) {
    int ch = nbase + nt * 16 + lm;
    float zb = bc[ch];
    float inv = rsqrtf(bnv[ch] + 1e-5f);
    float gsc = inv * bng[ch];
    float mm = bnm[ch], ab = bnb[ch];
    #pragma unroll
    for (int rr = 0; rr < 4; ++rr) {
      int pos = mtile * 16 + g * 4 + rr;
      float z = acc[nt][rr] + zb;
      z = (z - mm) * gsc + ab;
      fst[pos * 130 + ch] = fmaxf(z, 0.f);
    }
  }
  __syncthreads();
  #pragma unroll
  for (int e4 = 0; e4 < 4; ++e4) {
    f32x4 ov;
    #pragma unroll
    for (int j = 0; j < 4; ++j) ov[j] = fst[(rt * 16 + e4 * 4 + j) * 130 + ct];
    *(f32x4*)(outp + gbase + 4 * e4) = ov;
  }
}

// ---------------- launcher ----------------
extern "C" void kernel_launch(void* const* d_in, const int* in_sizes, int n_in,
                              void* d_out, int out_size, void* d_ws, size_t ws_size,
                              hipStream_t stream) {
  const float* x       = (const float*)d_in[0];
  const float* y       = (const float*)d_in[1];
  const float* ca_w1   = (const float*)d_in[2];
  const float* ca_b1   = (const float*)d_in[3];
  const float* ca_w2   = (const float*)d_in[4];
  const float* ca_b2   = (const float*)d_in[5];
  const float* final_w = (const float*)d_in[6];
  const float* final_b = (const float*)d_in[7];
  const float* bn_g    = (const float*)d_in[8];
  const float* bn_b    = (const float*)d_in[9];
  const float* bn_m    = (const float*)d_in[10];
  const float* bn_v    = (const float*)d_in[11];
  const float* q_dw_w  = (const float*)d_in[12];
  const float* q_dw_b  = (const float*)d_in[13];
  const float* q_pw_w  = (const float*)d_in[14];
  const float* q_pw_b  = (const float*)d_in[15];
  const float* k_dw_w  = (const float*)d_in[16];
  const float* k_dw_b  = (const float*)d_in[17];
  const float* k_pw_w  = (const float*)d_in[18];
  const float* k_pw_b  = (const float*)d_in[19];
  const float* v_dw_w  = (const float*)d_in[20];
  const float* v_dw_b  = (const float*)d_in[21];
  const float* v_pw_w  = (const float*)d_in[22];
  const float* v_pw_b  = (const float*)d_in[23];
  const float* p_dw_w  = (const float*)d_in[24];
  const float* p_dw_b  = (const float*)d_in[25];
  const float* p_pw_w  = (const float*)d_in[26];
  const float* p_pw_b  = (const float*)d_in[27];

  char* ws = (char*)d_ws;
  float* sums = (float*)(ws + 0);                       // 8 KB
  float* cab  = (float*)(ws + 8192);                    // 8 KB
  unsigned short* Wqkv = (unsigned short*)(ws + 16384); // mats 0..2 (96 KB)
  unsigned short* W3   = Wqkv + 3 * 16384;              // mats 3..5 (96 KB)
  float* bc   = (float*)(ws + 212992);                  // 512 B
  unsigned short* W2b  = (unsigned short*)(ws + 213504);// 8 x 32 KB
  unsigned short* outb = (unsigned short*)(ws + (1 << 20));  // 33.5 MB bf16

  k_pool<<<2048, 256, 0, stream>>>(x, y, sums);
  k_ca<<<8, 256, 0, stream>>>(sums, ca_w1, ca_b1, ca_w2, ca_b2, cab);
  k_prep<<<1792, 128, 0, stream>>>(q_pw_w, k_pw_w, v_pw_w, final_w, final_b,
                                   p_pw_w, p_pw_b, cab, Wqkv, W2b, bc);
  k_qkv_attn<<<4096, 256, 0, stream>>>(x, y, cab,
      q_dw_w, q_dw_b, k_dw_w, k_dw_b, v_dw_w, v_dw_b,
      Wqkv, q_pw_b, k_pw_b, v_pw_b, outb);
  k_final<<<4096, 256, 0, stream>>>(x, y, outb,
      p_dw_w, p_dw_b, W3, W2b, bc,
      bn_g, bn_b, bn_m, bn_v, (float*)d_out);
}

// Round 11
// 358.822 us; speedup vs baseline: 1.1099x; 1.1099x over previous
//
#include <hip/hip_runtime.h>

typedef __attribute__((ext_vector_type(8))) short short8;
typedef __attribute__((ext_vector_type(4))) float f32x4;
typedef __attribute__((ext_vector_type(2))) unsigned u32x2;
typedef __attribute__((ext_vector_type(4))) unsigned u32x4;

static constexpr int C_ = 128, H_ = 128, W_ = 128;
static constexpr int HW_ = H_ * W_;
static constexpr int CHW_ = C_ * HW_;

__device__ __forceinline__ unsigned short f2b(float f) {
  union { float f; unsigned u; } cv; cv.f = f;
  unsigned r = cv.u + 0x7FFFu + ((cv.u >> 16) & 1u);
  return (unsigned short)(r >> 16);
}
__device__ __forceinline__ float uasf(unsigned u) {
  union { unsigned u; float f; } cv; cv.u = u; return cv.f;
}
// swizzled byte offset within a 64-row x 256B-row LDS tile
__device__ __forceinline__ int swzo(int pos, int byteInRow) {
  return pos * 256 + (byteInRow ^ ((pos & 7) << 4));
}

// ---------------- K1: per-(b, channel-of-concat) sums ----------------
__global__ __launch_bounds__(256) void k_pool(const float* __restrict__ x,
                                              const float* __restrict__ y,
                                              float* __restrict__ sums) {
  int blk = blockIdx.x;
  int b = blk >> 8, c = blk & 255;
  const float* src = (c < C_) ? (x + (size_t)b * CHW_ + (size_t)c * HW_)
                              : (y + (size_t)b * CHW_ + (size_t)(c - C_) * HW_);
  const float4* s4 = (const float4*)src;
  float acc = 0.f;
  for (int i = threadIdx.x; i < HW_ / 4; i += 256) {
    float4 v = s4[i];
    acc += v.x + v.y + v.z + v.w;
  }
  for (int off = 32; off; off >>= 1) acc += __shfl_down(acc, off, 64);
  __shared__ float red[4];
  int lane = threadIdx.x & 63, wv = threadIdx.x >> 6;
  if (lane == 0) red[wv] = acc;
  __syncthreads();
  if (threadIdx.x == 0) sums[blk] = red[0] + red[1] + red[2] + red[3];
}

// ---------------- K2: channel attention ----------------
__global__ __launch_bounds__(256) void k_ca(const float* __restrict__ sums,
                                            const float* __restrict__ w1,
                                            const float* __restrict__ b1,
                                            const float* __restrict__ w2,
                                            const float* __restrict__ b2,
                                            float* __restrict__ ca) {
  int b = blockIdx.x;
  __shared__ float pooled[256];
  __shared__ float hb[16];
  int t = threadIdx.x;
  pooled[t] = sums[b * 256 + t] * (1.f / 16384.f);
  __syncthreads();
  if (t < 16) {
    float s = b1[t];
    for (int j = 0; j < 256; ++j) s += w1[t * 256 + j] * pooled[j];
    hb[t] = fmaxf(s, 0.f);
  }
  __syncthreads();
  float s = b2[t];
  for (int r = 0; r < 16; ++r) s += w2[t * 16 + r] * hb[r];
  ca[b * 256 + t] = 1.f / (1.f + __expf(-s));
}

// ---------------- K3: weight prep ----------------
__global__ __launch_bounds__(128) void k_prep(
    const float* __restrict__ qpw, const float* __restrict__ kpw,
    const float* __restrict__ vpw,
    const float* __restrict__ fw, const float* __restrict__ fb,
    const float* __restrict__ ppw, const float* __restrict__ ppb,
    const float* __restrict__ cab,
    unsigned short* __restrict__ Wb, unsigned short* __restrict__ W2b,
    float* __restrict__ bc) {
  int blk = blockIdx.x, c = threadIdx.x;
  if (blk < 768) {
    int mat = blk >> 7, o = blk & 127;
    float v = 0.f;
    if (mat == 0) v = qpw[o * 128 + c];
    else if (mat == 1) v = kpw[o * 128 + c];
    else if (mat == 2) v = vpw[o * 128 + c];
    else if (mat == 3) {
      float a = 0.f;
      for (int m = 0; m < 128; ++m) a += fw[o * 384 + 256 + m] * ppw[m * 128 + c];
      v = a;
      if (c == 0) {
        float bb = fb[o];
        for (int m = 0; m < 128; ++m) bb += fw[o * 384 + 256 + m] * ppb[m];
        bc[o] = bb;
      }
    } else if (mat == 4) v = fw[o * 384 + c];
    else v = 0.f;
    Wb[((size_t)mat << 14) + o * 128 + c] = f2b(v);
  } else {
    int bb = (blk - 768) >> 7, o = blk & 127;
    W2b[((size_t)bb << 14) + o * 128 + c] =
        f2b(fw[o * 384 + 128 + c] * cab[bb * 256 + 128 + c]);
  }
}

// ---------------- K4: r4 structure + pipelined GEMM weight loads ------------
// 16x4 tiles, 512 thr, launch_bounds(512,4). LDS 80K: QS KS VT A1 A2;
// halo aliases [16K,44K); scr aliases A1; OS aliases A2.
__global__ __launch_bounds__(512, 4) void k_qkv_attn(
    const float* __restrict__ x, const float* __restrict__ y,
    const float* __restrict__ cab,
    const float* __restrict__ qdw, const float* __restrict__ qdb,
    const float* __restrict__ kdw, const float* __restrict__ kdb,
    const float* __restrict__ vdw, const float* __restrict__ vdb,
    const unsigned short* __restrict__ Wqkv,
    const float* __restrict__ qpb, const float* __restrict__ kpb,
    const float* __restrict__ vpb,
    unsigned short* __restrict__ outb) {
  __shared__ __align__(16) char lds[81920];
  constexpr int QS = 0, KS = 16384, VT = 32768, A1 = 49152, A2 = 65536;
  constexpr int HA = 16384, SCR = 49152, OS = 65536;

  const int t = threadIdx.x;
  const int l = t & 63;
  const int w = t >> 6;
  const int lm = l & 15, g = l >> 4;
  const int bs = ((blockIdx.x & 7) << 8) | (blockIdx.x >> 3);  // XCD-chunked
  const int b = bs >> 8, tr = bs & 255;
  const int y0 = (tr >> 3) << 2, x0 = (tr & 7) << 4;
  const int ct = t & 127, rowt = t >> 7;
  unsigned short* hal = (unsigned short*)(lds + HA);  // [hrow][c] pitch 18 u16

  auto halo_issue = [&](const float* src, f32x4 (*hv)[6]) {
    #pragma unroll
    for (int tk = 0; tk < 2; ++tk) {
      int task = t + tk * 512;
      bool tv = task < 768;
      int c = task & 127, hr = task >> 7;
      int gy = y0 - 1 + hr;
      bool rowok = tv && ((unsigned)gy < 128u);
      const float* rsrc = src + (size_t)c * HW_ + gy * W_;
      #pragma unroll
      for (int ck = 0; ck < 6; ++ck) {
        int gxc = x0 - 4 + 4 * ck;
        bool ok = rowok && ((unsigned)gxc < 125u);
        hv[tk][ck] = ok ? *(const f32x4*)(rsrc + gxc) : f32x4{0.f, 0.f, 0.f, 0.f};
      }
    }
  };
  auto halo_write = [&](const f32x4 (*hv)[6]) {
    #pragma unroll
    for (int tk = 0; tk < 2; ++tk) {
      int task = t + tk * 512;
      if (task < 768) {
        int base = ((task >> 7) * 128 + (task & 127)) * 18;
        const float* f = (const float*)hv[tk];
        #pragma unroll
        for (int e = 0; e < 9; ++e) {
          unsigned u = (unsigned)f2b(f[2 * e + 3]) |
                       ((unsigned)f2b(f[2 * e + 4]) << 16);
          *(unsigned*)(hal + base + 2 * e) = u;
        }
      }
    }
  };

  auto dw_one = [&](const float* wdw, const float* bdw, const float* cas,
                    int aOff) {
    const float* wp = wdw + ct * 9;
    float wr[9];
    #pragma unroll
    for (int k2 = 0; k2 < 9; ++k2) wr[k2] = wp[k2];
    float cam = cas[ct], bb = bdw[ct];
    float o[16];
    #pragma unroll
    for (int px = 0; px < 16; ++px) o[px] = 0.f;
    #pragma unroll
    for (int rr = 0; rr < 3; ++rr) {
      int base = ((rowt + rr) * 128 + ct) * 18;
      unsigned rp[9];
      #pragma unroll
      for (int e = 0; e < 9; ++e) rp[e] = *(const unsigned*)(hal + base + 2 * e);
      float rv[18];
      #pragma unroll
      for (int e = 0; e < 9; ++e) {
        rv[2 * e] = uasf(rp[e] << 16);
        rv[2 * e + 1] = uasf(rp[e] & 0xffff0000u);
      }
      #pragma unroll
      for (int px = 0; px < 16; ++px)
        o[px] += rv[px] * wr[3 * rr] + rv[px + 1] * wr[3 * rr + 1] +
                 rv[px + 2] * wr[3 * rr + 2];
    }
    #pragma unroll
    for (int px = 0; px < 16; ++px)
      *(unsigned short*)(lds + aOff + swzo(rowt * 16 + px, 2 * ct)) =
          f2b(o[px] * cam + bb);
  };
  auto dw_kv = [&](const float* kw, const float* kb2, const float* vw,
                   const float* vb2, const float* cas) {
    const float* kp = kw + ct * 9;
    const float* vp = vw + ct * 9;
    float wk[9], wv2[9];
    #pragma unroll
    for (int k2 = 0; k2 < 9; ++k2) { wk[k2] = kp[k2]; wv2[k2] = vp[k2]; }
    float cam = cas[ct], kbb = kb2[ct], vbb = vb2[ct];
    float ok[16], ov[16];
    #pragma unroll
    for (int px = 0; px < 16; ++px) { ok[px] = 0.f; ov[px] = 0.f; }
    #pragma unroll
    for (int rr = 0; rr < 3; ++rr) {
      int base = ((rowt + rr) * 128 + ct) * 18;
      unsigned rp[9];
      #pragma unroll
      for (int e = 0; e < 9; ++e) rp[e] = *(const unsigned*)(hal + base + 2 * e);
      float rv[18];
      #pragma unroll
      for (int e = 0; e < 9; ++e) {
        rv[2 * e] = uasf(rp[e] << 16);
        rv[2 * e + 1] = uasf(rp[e] & 0xffff0000u);
      }
      #pragma unroll
      for (int px = 0; px < 16; ++px) {
        ok[px] += rv[px] * wk[3 * rr] + rv[px + 1] * wk[3 * rr + 1] +
                  rv[px + 2] * wk[3 * rr + 2];
        ov[px] += rv[px] * wv2[3 * rr] + rv[px + 1] * wv2[3 * rr + 1] +
                  rv[px + 2] * wv2[3 * rr + 2];
      }
    }
    #pragma unroll
    for (int px = 0; px < 16; ++px) {
      int so = swzo(rowt * 16 + px, 2 * ct);
      *(unsigned short*)(lds + A1 + so) = f2b(ok[px] * cam + kbb);
      *(unsigned short*)(lds + A2 + so) = f2b(ov[px] * cam + vbb);
    }
  };

  const int mtile = w & 3, nbase = (w >> 2) * 64;

  // pipelined GEMM: hoist all 4 a-frags; prefetch next ks weight group
  auto gemm_qk = [&](int aOff, const unsigned short* Wm, const float* bias,
                     int dstOff) {
    f32x4 acc[4];
    #pragma unroll
    for (int nt = 0; nt < 4; ++nt) acc[nt] = f32x4{0.f, 0.f, 0.f, 0.f};
    short8 a4[4];
    #pragma unroll
    for (int ks = 0; ks < 4; ++ks)
      a4[ks] = *(const short8*)(lds + aOff +
                 swzo(mtile * 16 + lm, ks * 64 + g * 16));
    short8 wf[4];
    #pragma unroll
    for (int nt = 0; nt < 4; ++nt)
      wf[nt] = *(const short8*)(Wm + (nbase + nt * 16 + lm) * 128 + g * 8);
    #pragma unroll
    for (int ks = 0; ks < 4; ++ks) {
      short8 wn[4];
      if (ks < 3) {
        #pragma unroll
        for (int nt = 0; nt < 4; ++nt)
          wn[nt] = *(const short8*)(Wm + (nbase + nt * 16 + lm) * 128 +
                                    (ks + 1) * 32 + g * 8);
      }
      #pragma unroll
      for (int nt = 0; nt < 4; ++nt)
        acc[nt] = __builtin_amdgcn_mfma_f32_16x16x32_bf16(a4[ks], wf[nt], acc[nt], 0, 0, 0);
      if (ks < 3) {
        #pragma unroll
        for (int nt = 0; nt < 4; ++nt) wf[nt] = wn[nt];
      }
    }
    #pragma unroll
    for (int nt = 0; nt < 4; ++nt) {
      int ch = nbase + nt * 16 + lm;
      float bv = bias[ch];
      #pragma unroll
      for (int r2 = 0; r2 < 4; ++r2) {
        int pos = mtile * 16 + g * 4 + r2;
        *(unsigned short*)(lds + dstOff + swzo(pos, 2 * ch)) =
            f2b(acc[nt][r2] + bv);
      }
    }
  };
  // V gemm -> transposed window-major tile VT[ch][col ^ ((ch&7)<<3)]
  auto gemm_v = [&](int aOff, const unsigned short* Wm, const float* bias) {
    f32x4 acc[4];
    #pragma unroll
    for (int nt = 0; nt < 4; ++nt) acc[nt] = f32x4{0.f, 0.f, 0.f, 0.f};
    short8 a4[4];
    #pragma unroll
    for (int ks = 0; ks < 4; ++ks)
      a4[ks] = *(const short8*)(lds + aOff +
                 swzo(mtile * 16 + lm, ks * 64 + g * 16));
    short8 wf[4];
    #pragma unroll
    for (int nt = 0; nt < 4; ++nt)
      wf[nt] = *(const short8*)(Wm + (nbase + nt * 16 + lm) * 128 + g * 8);
    #pragma unroll
    for (int ks = 0; ks < 4; ++ks) {
      short8 wn[4];
      if (ks < 3) {
        #pragma unroll
        for (int nt = 0; nt < 4; ++nt)
          wn[nt] = *(const short8*)(Wm + (nbase + nt * 16 + lm) * 128 +
                                    (ks + 1) * 32 + g * 8);
      }
      #pragma unroll
      for (int nt = 0; nt < 4; ++nt)
        acc[nt] = __builtin_amdgcn_mfma_f32_16x16x32_bf16(a4[ks], wf[nt], acc[nt], 0, 0, 0);
      if (ks < 3) {
        #pragma unroll
        for (int nt = 0; nt < 4; ++nt) wf[nt] = wn[nt];
      }
    }
    #pragma unroll
    for (int nt = 0; nt < 4; ++nt) {
      int ch = nbase + nt * 16 + lm;
      float bv = bias[ch];
      int col = (g * 16 + mtile * 4) ^ ((ch & 7) << 3);
      unsigned lo = (unsigned)f2b(acc[nt][0] + bv) |
                    ((unsigned)f2b(acc[nt][1] + bv) << 16);
      unsigned hi = (unsigned)f2b(acc[nt][2] + bv) |
                    ((unsigned)f2b(acc[nt][3] + bv) << 16);
      *(u32x2*)(lds + VT + ch * 128 + 2 * col) = u32x2{lo, hi};
    }
  };

  const float* cax = cab + b * 256;
  const float* cay = cax + 128;

  f32x4 hy[2][6], hx[2][6];
  halo_issue(y + (size_t)b * CHW_, hy);
  halo_issue(x + (size_t)b * CHW_, hx);
  halo_write(hy);
  __syncthreads();
  dw_one(qdw, qdb, cay, A1);          // x-halo loads still in flight
  __syncthreads();
  halo_write(hx);                     // halo region free (y reads done)
  gemm_qk(A1, Wqkv, qpb, QS);
  __syncthreads();
  dw_kv(kdw, kdb, vdw, vdb, cax);
  __syncthreads();
  gemm_qk(A1, Wqkv + 16384, kpb, KS); // KS aliases dead halo
  gemm_v(A2, Wqkv + 32768, vpb);
  __syncthreads();

  // ---- MFMA window attention: wave = head, 4 windows sequential ----
  {
    const int h = w;
    const int chb = h * 32;
    char* scr = lds + SCR + w * 512;
    const short8 zz = {};
    #pragma unroll
    for (int wi = 0; wi < 4; ++wi) {
      int rowp = (lm >> 2) * 16 + wi * 4 + (lm & 3);
      short8 avf = zz, bvf = zz;
      if (g < 2) {
        avf = *(const short8*)(lds + KS + swzo(rowp, chb + g * 16));
        bvf = *(const short8*)(lds + QS + swzo(rowp, chb + g * 16));
      }
      f32x4 st = __builtin_amdgcn_mfma_f32_16x16x32_bf16(
          avf, bvf, f32x4{0.f, 0.f, 0.f, 0.f}, 0, 0, 0);
      float s0 = st[0] * 0.25f, s1 = st[1] * 0.25f,
            s2 = st[2] * 0.25f, s3 = st[3] * 0.25f;
      float mx = fmaxf(fmaxf(s0, s1), fmaxf(s2, s3));
      mx = fmaxf(mx, __shfl_xor(mx, 16, 64));
      mx = fmaxf(mx, __shfl_xor(mx, 32, 64));
      float e0 = __expf(s0 - mx), e1 = __expf(s1 - mx),
            e2 = __expf(s2 - mx), e3 = __expf(s3 - mx);
      float sm = e0 + e1 + e2 + e3;
      sm += __shfl_xor(sm, 16, 64);
      sm += __shfl_xor(sm, 32, 64);
      float rl = 1.f / sm;
      unsigned p0 = (unsigned)f2b(e0 * rl) | ((unsigned)f2b(e1 * rl) << 16);
      unsigned p1 = (unsigned)f2b(e2 * rl) | ((unsigned)f2b(e3 * rl) << 16);
      *(u32x2*)(scr + lm * 32 + g * 8) = u32x2{p0, p1};
      short8 pb2 = zz, va = zz;
      if (g < 2) {
        pb2 = *(const short8*)(scr + lm * 32 + g * 16);
        int ch = h * 16 + lm;
        va = *(const short8*)(lds + VT + ch * 128 +
                              2 * ((wi * 16 + g * 8) ^ ((ch & 7) << 3)));
      }
      f32x4 ot = __builtin_amdgcn_mfma_f32_16x16x32_bf16(
          va, pb2, f32x4{0.f, 0.f, 0.f, 0.f}, 0, 0, 0);
      unsigned o0 = (unsigned)f2b(ot[0]) | ((unsigned)f2b(ot[1]) << 16);
      unsigned o1 = (unsigned)f2b(ot[2]) | ((unsigned)f2b(ot[3]) << 16);
      *(u32x2*)(lds + OS + swzo(rowp, chb + g * 8)) = u32x2{o0, o1};
    }
  }
  __syncthreads();
  {
    unsigned short* dst = outb + (size_t)b * CHW_ + (size_t)ct * HW_ +
                          (y0 + rowt) * W_ + x0;
    unsigned v[8];
    #pragma unroll
    for (int j = 0; j < 8; ++j) {
      unsigned lo = *(const unsigned short*)(lds + OS + swzo(rowt * 16 + 2 * j, 2 * ct));
      unsigned hi = *(const unsigned short*)(lds + OS + swzo(rowt * 16 + 2 * j + 1, 2 * ct));
      v[j] = lo | (hi << 16);
    }
    *(u32x4*)(dst) = u32x4{v[0], v[1], v[2], v[3]};
    *(u32x4*)(dst + 8) = u32x4{v[4], v[5], v[6], v[7]};
  }
}

// ---------------- K5: proj-dw + 3 accumulated MFMA GEMMs + BN + ReLU --------
// 16x4 tiles. LDS 49K: A1[0,16K), halo (768 x 22 u16 = 33.8K)/fst alias @16K.
// wf-only pipeline (keeps VGPR under the 85 / 3-block ceiling).
__global__ __launch_bounds__(512, 4) void k_final(
    const float* __restrict__ x, const float* __restrict__ y,
    const unsigned short* __restrict__ outb,
    const float* __restrict__ pdw, const float* __restrict__ pdb,
    const unsigned short* __restrict__ W3,
    const unsigned short* __restrict__ W2b,
    const float* __restrict__ bc,
    const float* __restrict__ bng, const float* __restrict__ bnb,
    const float* __restrict__ bnm, const float* __restrict__ bnv,
    float* __restrict__ outp) {
  __shared__ __align__(16) char lds[50176];
  constexpr int A1 = 0, HA = 16384;

  const int t = threadIdx.x, l = t & 63, w = t >> 6;
  const int lm = l & 15, g = l >> 4;
  const int bs = ((blockIdx.x & 7) << 8) | (blockIdx.x >> 3);
  const int b = bs >> 8, tr = bs & 255;
  const int y0 = (tr >> 3) << 2, x0 = (tr & 7) << 4;
  const int ct = t & 127, rowt = t >> 7;
  unsigned short* hal = (unsigned short*)(lds + HA);
  const int mtile = w & 3, nbase = (w >> 2) * 64;

  f32x4 acc[4];
  #pragma unroll
  for (int nt = 0; nt < 4; ++nt) acc[nt] = f32x4{0.f, 0.f, 0.f, 0.f};

  auto gemm_acc = [&](const unsigned short* Wm) {
    short8 wf[4];
    #pragma unroll
    for (int nt = 0; nt < 4; ++nt)
      wf[nt] = *(const short8*)(Wm + (nbase + nt * 16 + lm) * 128 + g * 8);
    #pragma unroll
    for (int ks = 0; ks < 4; ++ks) {
      short8 wn[4];
      if (ks < 3) {
        #pragma unroll
        for (int nt = 0; nt < 4; ++nt)
          wn[nt] = *(const short8*)(Wm + (nbase + nt * 16 + lm) * 128 +
                                    (ks + 1) * 32 + g * 8);
      }
      short8 a = *(const short8*)(lds + A1 +
                   swzo(mtile * 16 + lm, ks * 64 + g * 16));
      #pragma unroll
      for (int nt = 0; nt < 4; ++nt)
        acc[nt] = __builtin_amdgcn_mfma_f32_16x16x32_bf16(a, wf[nt], acc[nt], 0, 0, 0);
      if (ks < 3) {
        #pragma unroll
        for (int nt = 0; nt < 4; ++nt) wf[nt] = wn[nt];
      }
    }
  };

  const size_t gbase = (size_t)b * CHW_ + (size_t)ct * HW_ +
                       (size_t)(y0 + rowt) * W_ + x0;
  f32x4 xv[4], yv[4];
  #pragma unroll
  for (int e = 0; e < 4; ++e) {
    xv[e] = *(const f32x4*)(x + gbase + 4 * e);
    yv[e] = *(const f32x4*)(y + gbase + 4 * e);
  }
  unsigned hreg[2][10];
  #pragma unroll
  for (int tk = 0; tk < 2; ++tk) {
    int task = t + tk * 512;
    bool tv = task < 768;
    int c = task & 127, hr = task >> 7;
    int gy = y0 - 1 + hr;
    bool rowok = tv && ((unsigned)gy < 128u);
    const unsigned short* hsrc = outb + (size_t)b * CHW_ + (size_t)c * HW_ + gy * W_;
    #pragma unroll
    for (int e = 0; e < 10; ++e) {
      int gx0 = x0 - 2 + 2 * e;
      bool okp = rowok && ((unsigned)gx0 < 127u);
      hreg[tk][e] = okp ? *(const unsigned*)(hsrc + gx0) : 0u;
    }
  }
  #pragma unroll
  for (int e = 0; e < 4; ++e)
    #pragma unroll
    for (int j = 0; j < 4; ++j)
      *(unsigned short*)(lds + A1 + swzo(rowt * 16 + 4 * e + j, 2 * ct)) =
          f2b(xv[e][j] * yv[e][j]);
  #pragma unroll
  for (int tk = 0; tk < 2; ++tk) {
    int task = t + tk * 512;
    if (task < 768) {
      int base = ((task >> 7) * 128 + (task & 127)) * 22;
      #pragma unroll
      for (int e = 0; e < 10; ++e)
        *(unsigned*)(hal + base + 2 * e) = hreg[tk][e];
    }
  }
  __syncthreads();
  gemm_acc(W3 + 16384);                 // fw1 on x*y
  __syncthreads();
  #pragma unroll
  for (int e = 0; e < 4; ++e)
    #pragma unroll
    for (int j = 0; j < 4; ++j)
      *(unsigned short*)(lds + A1 + swzo(rowt * 16 + 4 * e + j, 2 * ct)) =
          f2b(yv[e][j]);
  __syncthreads();
  gemm_acc(W2b + ((size_t)b << 14));    // fw2 * diag(ca_y)
  __syncthreads();
  {
    const float* wp = pdw + ct * 9;
    float wr[9];
    #pragma unroll
    for (int k2 = 0; k2 < 9; ++k2) wr[k2] = wp[k2];
    float bb = pdb[ct];
    float o[16];
    #pragma unroll
    for (int px = 0; px < 16; ++px) o[px] = 0.f;
    #pragma unroll
    for (int rr = 0; rr < 3; ++rr) {
      int base = ((rowt + rr) * 128 + ct) * 22;
      unsigned rp[10];
      #pragma unroll
      for (int e = 0; e < 10; ++e) rp[e] = *(const unsigned*)(hal + base + 2 * e);
      float rv[20];
      #pragma unroll
      for (int e = 0; e < 10; ++e) {
        rv[2 * e] = uasf(rp[e] << 16);
        rv[2 * e + 1] = uasf(rp[e] & 0xffff0000u);
      }
      #pragma unroll
      for (int px = 0; px < 16; ++px)
        o[px] += rv[px + 1] * wr[3 * rr] + rv[px + 2] * wr[3 * rr + 1] +
                 rv[px + 3] * wr[3 * rr + 2];
    }
    #pragma unroll
    for (int px = 0; px < 16; ++px)
      *(unsigned short*)(lds + A1 + swzo(rowt * 16 + px, 2 * ct)) =
          f2b(o[px] + bb);
  }
  __syncthreads();
  gemm_acc(W3);                          // folded Wc
  float* fst = (float*)(lds + HA);
  #pragma unroll
  for (int nt = 0; nt < 4; ++nt) {
    int ch = nbase + nt * 16 + lm;
    float zb = bc[ch];
    float inv = rsqrtf(bnv[ch] + 1e-5f);
    float gsc = inv * bng[ch];
    float mm = bnm[ch], ab = bnb[ch];
    #pragma unroll
    for (int r2 = 0; r2 < 4; ++r2) {
      int pos = mtile * 16 + g * 4 + r2;
      float z = acc[nt][r2] + zb;
      z = (z - mm) * gsc + ab;
      fst[pos * 130 + ch] = fmaxf(z, 0.f);
    }
  }
  __syncthreads();
  #pragma unroll
  for (int e4 = 0; e4 < 4; ++e4) {
    f32x4 ov;
    #pragma unroll
    for (int j = 0; j < 4; ++j) ov[j] = fst[(rowt * 16 + e4 * 4 + j) * 130 + ct];
    *(f32x4*)(outp + gbase + 4 * e4) = ov;
  }
}

// ---------------- launcher ----------------
extern "C" void kernel_launch(void* const* d_in, const int* in_sizes, int n_in,
                              void* d_out, int out_size, void* d_ws, size_t ws_size,
                              hipStream_t stream) {
  const float* x       = (const float*)d_in[0];
  const float* y       = (const float*)d_in[1];
  const float* ca_w1   = (const float*)d_in[2];
  const float* ca_b1   = (const float*)d_in[3];
  const float* ca_w2   = (const float*)d_in[4];
  const float* ca_b2   = (const float*)d_in[5];
  const float* final_w = (const float*)d_in[6];
  const float* final_b = (const float*)d_in[7];
  const float* bn_g    = (const float*)d_in[8];
  const float* bn_b    = (const float*)d_in[9];
  const float* bn_m    = (const float*)d_in[10];
  const float* bn_v    = (const float*)d_in[11];
  const float* q_dw_w  = (const float*)d_in[12];
  const float* q_dw_b  = (const float*)d_in[13];
  const float* q_pw_w  = (const float*)d_in[14];
  const float* q_pw_b  = (const float*)d_in[15];
  const float* k_dw_w  = (const float*)d_in[16];
  const float* k_dw_b  = (const float*)d_in[17];
  const float* k_pw_w  = (const float*)d_in[18];
  const float* k_pw_b  = (const float*)d_in[19];
  const float* v_dw_w  = (const float*)d_in[20];
  const float* v_dw_b  = (const float*)d_in[21];
  const float* v_pw_w  = (const float*)d_in[22];
  const float* v_pw_b  = (const float*)d_in[23];
  const float* p_dw_w  = (const float*)d_in[24];
  const float* p_dw_b  = (const float*)d_in[25];
  const float* p_pw_w  = (const float*)d_in[26];
  const float* p_pw_b  = (const float*)d_in[27];

  char* ws = (char*)d_ws;
  float* sums = (float*)(ws + 0);                       // 8 KB
  float* cab  = (float*)(ws + 8192);                    // 8 KB
  unsigned short* Wqkv = (unsigned short*)(ws + 16384); // mats 0..2 (96 KB)
  unsigned short* W3   = Wqkv + 3 * 16384;              // mats 3..5 (96 KB)
  float* bc   = (float*)(ws + 212992);                  // 512 B
  unsigned short* W2b  = (unsigned short*)(ws + 213504);// 8 x 32 KB
  unsigned short* outb = (unsigned short*)(ws + (1 << 20));  // 33.5 MB bf16

  k_pool<<<2048, 256, 0, stream>>>(x, y, sums);
  k_ca<<<8, 256, 0, stream>>>(sums, ca_w1, ca_b1, ca_w2, ca_b2, cab);
  k_prep<<<1792, 128, 0, stream>>>(q_pw_w, k_pw_w, v_pw_w, final_w, final_b,
                                   p_pw_w, p_pw_b, cab, Wqkv, W2b, bc);
  k_qkv_attn<<<2048, 512, 0, stream>>>(x, y, cab,
      q_dw_w, q_dw_b, k_dw_w, k_dw_b, v_dw_w, v_dw_b,
      Wqkv, q_pw_b, k_pw_b, v_pw_b, outb);
  k_final<<<2048, 512, 0, stream>>>(x, y, outb,
      p_dw_w, p_dw_b, W3, W2b, bc,
      bn_g, bn_b, bn_m, bn_v, (float*)d_out);
}